// Round 20
// baseline (439.967 us; speedup 1.0000x reference)
//
#include <hip/hip_runtime.h>

typedef unsigned short u16;
typedef __attribute__((ext_vector_type(8))) short bf16x8;
typedef __attribute__((ext_vector_type(4))) float f32x4;
typedef __attribute__((ext_vector_type(16))) float f32x16;

#define H_    24
#define DH_   128
#define DIM_  3072
#define NQKV_ 9216
#define SIMG_ 2048
#define STXT_ 256
#define SQ_   2304
#define SL_   0.1275258646912204f

__device__ __forceinline__ float bf2f(u16 h) {
  union { unsigned u; float f; } x; x.u = ((unsigned)h) << 16; return x.f;
}
__device__ __forceinline__ u16 f2bf(float f) {
  union { float f; unsigned u; } x; x.f = f;
  unsigned r = x.u + 0x7FFFu + ((x.u >> 16) & 1u);
  return (u16)(r >> 16);
}
__device__ __forceinline__ unsigned cvt_pk_bf16(float lo, float hi) {
  unsigned r;
  asm("v_cvt_pk_bf16_f32 %0, %1, %2" : "=v"(r) : "v"(lo), "v"(hi));
  return r;
}

__device__ __forceinline__ void gld16(const u16* g, u16* l) {
  __builtin_amdgcn_global_load_lds(
      (const __attribute__((address_space(1))) unsigned*)g,
      (__attribute__((address_space(3))) unsigned*)l, 16, 0, 0);
}

// shared transpose tile body (fp32 [R][C] -> bf16 [C][R], 64x64)
__device__ __forceinline__ void transpose_tile(const float* __restrict__ in,
                                               u16* __restrict__ out,
                                               int R, int C, int bc, int br,
                                               u16 (*tile)[72], int t) {
  const int tx = t & 15, ty = t >> 4;
#pragma unroll
  for (int i = 0; i < 4; ++i) {
    const int r = ty + i * 16;
    float4 v = *(const float4*)(in + (size_t)(br + r) * C + bc + tx * 4);
    ushort4 o;
    o.x = f2bf(v.x); o.y = f2bf(v.y); o.z = f2bf(v.z); o.w = f2bf(v.w);
    *(ushort4*)&tile[r][tx * 4] = o;
  }
  __syncthreads();
#pragma unroll
  for (int i = 0; i < 4; ++i) {
    const int c = ty + i * 16;
    ushort4 v;
    v.x = tile[tx * 4 + 0][c];
    v.y = tile[tx * 4 + 1][c];
    v.z = tile[tx * 4 + 2][c];
    v.w = tile[tx * 4 + 3][c];
    *(ushort4*)(out + (size_t)(bc + c) * R + br + tx * 4) = v;
  }
}

// ===== k_pre: f2b of both activations + both QKV weight transposes =========
__global__ __launch_bounds__(256) void k_pre(
    const float* __restrict__ hidden, u16* __restrict__ hidden_bf, int n0,
    const float* __restrict__ encoder, u16* __restrict__ encoder_bf, int n1,
    const float* __restrict__ w0, u16* __restrict__ wt0,
    const float* __restrict__ w1, u16* __restrict__ wt1) {
  __shared__ __align__(16) u16 tile[64][72];
  const int t = threadIdx.x;
  const int nf2b = (n0 + n1) / 1024;
  if ((int)blockIdx.x < nf2b) {
    int i = (blockIdx.x * 256 + t) * 4;
    const float* in = hidden;
    u16* out = hidden_bf;
    int n = n0;
    if (i >= n0) { i -= n0; in = encoder; out = encoder_bf; n = n1; }
    if (i < n) {
      float4 v = *(const float4*)(in + i);
      ushort4 o;
      o.x = f2bf(v.x); o.y = f2bf(v.y); o.z = f2bf(v.z); o.w = f2bf(v.w);
      *(ushort4*)(out + i) = o;
    }
    return;
  }
  const int blk = blockIdx.x - nf2b;
  const int nxy = (NQKV_ / 64) * (DIM_ / 64);  // 144*48 per weight
  const int z = blk / nxy, rem = blk % nxy;
  const int bx = rem % (NQKV_ / 64), by = rem / (NQKV_ / 64);
  transpose_tile(z ? w1 : w0, z ? wt1 : wt0, DIM_, NQKV_,
                 bx * 64, by * 64, tile, t);
}

// --------- GEMM 128x128, BK=32, QUAD-buffered LDS, ONE barrier per K-tile,
// stage-2-ahead: tile i's loads issued 2 iters (~1800cy) before vmcnt(8)
// waits them -> 2x HBM latency cover. WAR-free with one barrier:
// iter i writes buf (i+2)&3; slowest concurrent readers use (i-1)&3 (差3).
// TWO problems fused per launch (tail-filling demux). ------------------------
template <bool F32OUT>
__global__ __launch_bounds__(256) void k_gemm_bt2(const u16* __restrict__ A0,
                                                  const u16* __restrict__ Bt0,
                                                  const float* __restrict__ bias0,
                                                  void* __restrict__ C0,
                                                  int M0,
                                                  const u16* __restrict__ A1,
                                                  const u16* __restrict__ Bt1,
                                                  const float* __restrict__ bias1,
                                                  void* __restrict__ C1,
                                                  int M1,
                                                  int N, int K, int nblk0) {
  __shared__ __align__(16) u16 As[4][128 * 32];  // 32 KB
  __shared__ __align__(16) u16 Bs[4][128 * 32];  // 32 KB
  const int t = threadIdx.x, w = t >> 6, l = t & 63;
  const int lr = l & 15, lg = l >> 4;
  const int wr = w >> 1, wc = w & 1;

  const u16 *A, *Bt;
  const float* bias;
  void* Cv;
  int M, wg, nwg;
  if ((int)blockIdx.x < nblk0) {
    A = A0; Bt = Bt0; bias = bias0; Cv = C0; M = M0;
    wg = blockIdx.x; nwg = nblk0;
  } else {
    A = A1; Bt = Bt1; bias = bias1; Cv = C1; M = M1;
    wg = blockIdx.x - nblk0; nwg = gridDim.x - nblk0;
  }
  const int nbm = M >> 7;
  if ((nwg & 7) == 0) {
    const int c = nwg >> 3;
    wg = (wg & 7) * c + (wg >> 3);
  }
  const int bm = (wg % nbm) * 128, bn = (wg / nbm) * 128;

  f32x4 acc[4][4];
#pragma unroll
  for (int i = 0; i < 4; ++i)
#pragma unroll
    for (int j = 0; j < 4; ++j) acc[i][j] = (f32x4){0.f, 0.f, 0.f, 0.f};

  const u16* Ag = A + (size_t)(bm + (t >> 2)) * K + (t & 3) * 8;
  const u16* Bg = Bt + (size_t)(bn + (t >> 2)) * K + (t & 3) * 8;

#define GSTAGE(buf)                                        \
  do {                                                     \
    gld16(Ag, &As[buf][t * 8]);                            \
    gld16(Ag + (size_t)64 * K, &As[buf][t * 8 + 2048]);    \
    gld16(Bg, &Bs[buf][t * 8]);                            \
    gld16(Bg + (size_t)64 * K, &Bs[buf][t * 8 + 2048]);    \
    Ag += 32; Bg += 32;                                    \
  } while (0)

  GSTAGE(0);  // tile 0
  GSTAGE(1);  // tile 1   (8 loads outstanding)
  const int nt = K >> 5;
  for (int tile = 0; tile < nt; ++tile) {
    const int cur = tile & 3;
    if (tile + 2 < nt) {
      GSTAGE((tile + 2) & 3);                              // 12 outstanding
      asm volatile("s_waitcnt vmcnt(8)" ::: "memory");     // tile i landed
    } else if (tile + 1 < nt) {
      asm volatile("s_waitcnt vmcnt(4)" ::: "memory");
    } else {
      asm volatile("s_waitcnt vmcnt(0)" ::: "memory");
    }
    __builtin_amdgcn_s_barrier();
    bf16x8 af[4], bfr[4];
#pragma unroll
    for (int i = 0; i < 4; ++i)
      af[i] = *(const bf16x8*)&As[cur][(wr * 64 + i * 16 + lr) * 32 + lg * 8];
#pragma unroll
    for (int j = 0; j < 4; ++j)
      bfr[j] = *(const bf16x8*)&Bs[cur][(wc * 64 + j * 16 + lr) * 32 + lg * 8];
#pragma unroll
    for (int i = 0; i < 4; ++i)
#pragma unroll
      for (int j = 0; j < 4; ++j)
        acc[i][j] = __builtin_amdgcn_mfma_f32_16x16x32_bf16(af[i], bfr[j], acc[i][j], 0, 0, 0);
    // no post-MFMA barrier: quad-buffer makes the WAR impossible
  }
#undef GSTAGE

#pragma unroll
  for (int j = 0; j < 4; ++j) {
    const int col = bn + wc * 64 + j * 16 + lr;
    const float bv = bias[col];
#pragma unroll
    for (int i = 0; i < 4; ++i) {
      const int row = bm + wr * 64 + i * 16 + lg * 4;
#pragma unroll
      for (int r = 0; r < 4; ++r) {
        const float v = acc[i][j][r] + bv;
        if constexpr (F32OUT)
          ((float*)Cv)[(size_t)(row + r) * N + col] = v;
        else
          ((u16*)Cv)[(size_t)(row + r) * N + col] = f2bf(v);
      }
    }
  }
}

// ===== k_prep: merged (k_vt | k_norm_rope) via block-range demux ============
__global__ __launch_bounds__(256) void k_prep(
    const u16* __restrict__ img_qkv, const u16* __restrict__ txt_qkv,
    const float* __restrict__ vid_cos, const float* __restrict__ vid_sin,
    const float* __restrict__ txt_cos, const float* __restrict__ txt_sin,
    const float* __restrict__ nq, const float* __restrict__ nk,
    const float* __restrict__ naq, const float* __restrict__ nak,
    u16* __restrict__ Qb, u16* __restrict__ Kb, u16* __restrict__ Vt) {
  __shared__ __align__(16) u16 tile[64][136];
  const int t = threadIdx.x;
  if (blockIdx.x < (SQ_ / 64) * H_) {
    const int h = blockIdx.x / (SQ_ / 64), sb = blockIdx.x % (SQ_ / 64);
    {
      const int row = t >> 2, cc = (t & 3) * 32;
      const int s = sb * 64 + row;
      const u16* src = (s < STXT_) ? (txt_qkv + (size_t)s * NQKV_)
                                   : (img_qkv + (size_t)(s - STXT_) * NQKV_);
      src += 2 * DIM_ + h * DH_ + cc;
#pragma unroll
      for (int u = 0; u < 4; ++u) {
        uint4 a = *(const uint4*)(src + u * 8);
        *(uint4*)&tile[row][cc + u * 8] = a;
      }
    }
    __syncthreads();
    {
      const int w = t >> 6, lane = t & 63;
#pragma unroll 4
      for (int dd = 0; dd < 32; ++dd) {
        const int d = w * 32 + dd;
        const int m = (d & 7) << 3;
        const u16 v = tile[lane][d];
        Vt[((size_t)h * DH_ + d) * SQ_ + sb * 64 + (lane ^ m)] = v;
      }
    }
    return;
  }
  const int wid = (blockIdx.x - (SQ_ / 64) * H_) * 4 + (t >> 6);
  const int lane = t & 63;
  const int h = wid % H_, s = wid / H_;

  const u16* src;
  const float *cp, *sp, *qw, *kw;
  if (s < STXT_) {
    src = txt_qkv + (size_t)s * NQKV_;
    cp = txt_cos + s * 64; sp = txt_sin + s * 64;
    qw = naq; kw = nak;
  } else {
    const int si = s - STXT_;
    src = img_qkv + (size_t)si * NQKV_;
    cp = vid_cos + si * 64; sp = vid_sin + si * 64;
    qw = nq; kw = nk;
  }
  const float c = cp[lane], sn = sp[lane];
  const size_t drow = ((size_t)h * SQ_ + s) * DH_;

  {
    ushort2 p = *(const ushort2*)(src + h * DH_ + 2 * lane);
    float x1 = bf2f(p.x), x2 = bf2f(p.y);
    float ss = x1 * x1 + x2 * x2;
#pragma unroll
    for (int m = 1; m < 64; m <<= 1) ss += __shfl_xor(ss, m);
    const float rr = rsqrtf(ss * (1.0f / 128.0f) + 1e-6f);
    const float xn1 = x1 * rr * qw[2 * lane];
    const float xn2 = x2 * rr * qw[2 * lane + 1];
    ushort2 o; o.x = f2bf(xn1 * c - xn2 * sn); o.y = f2bf(xn2 * c + xn1 * sn);
    *(ushort2*)(Qb + drow + 2 * lane) = o;
  }
  {
    ushort2 p = *(const ushort2*)(src + DIM_ + h * DH_ + 2 * lane);
    float x1 = bf2f(p.x), x2 = bf2f(p.y);
    float ss = x1 * x1 + x2 * x2;
#pragma unroll
    for (int m = 1; m < 64; m <<= 1) ss += __shfl_xor(ss, m);
    const float rr = rsqrtf(ss * (1.0f / 128.0f) + 1e-6f);
    const float xn1 = x1 * rr * kw[2 * lane];
    const float xn2 = x2 * rr * kw[2 * lane + 1];
    ushort2 o; o.x = f2bf(xn1 * c - xn2 * sn); o.y = f2bf(xn2 * c + xn1 * sn);
    const int col = (2 * lane) ^ ((s & 7) << 3);
    *(ushort2*)(Kb + drow + col) = o;
  }
}

// === k_attn_f: flash attention + out-weight transposes in ONE launch ========
__global__ __launch_bounds__(256, 2) void k_attn_f(
    const u16* __restrict__ Qb, const u16* __restrict__ Kb,
    const u16* __restrict__ Vt, u16* __restrict__ attnb,
    const float* __restrict__ w0, u16* __restrict__ wt0,
    const float* __restrict__ w1, u16* __restrict__ wt1) {
  __shared__ __align__(16) u16 Ks[2][64 * 128];
  __shared__ __align__(16) u16 Vs[2][128 * 64];
  const int t = threadIdx.x;
  if (blockIdx.x >= (SQ_ / 128) * H_) {
    const int blk = blockIdx.x - (SQ_ / 128) * H_;
    const int nxy = (DIM_ / 64) * (DIM_ / 64);  // 2304
    const int z = blk / nxy, rem = blk % nxy;
    const int bx = rem % (DIM_ / 64), by = rem / (DIM_ / 64);
    u16 (*tile)[72] = (u16(*)[72]) & Ks[0][0];
    transpose_tile(z ? w1 : w0, z ? wt1 : wt0, DIM_, DIM_,
                   bx * 64, by * 64, tile, t);
    return;
  }
  const int w = t >> 6, l = t & 63;
  const int lo = l & 31, hi = l >> 5;

  const int bid = blockIdx.x;
  const int xcd = bid & 7, jj = bid >> 3;
  const int h = xcd * 3 + jj / 18;
  const int qb = jj % 18;

  const int q0 = qb * 128 + w * 32;
  const size_t head = (size_t)h * SQ_ * DH_;

  bf16x8 qf[8];
  {
    const u16* qp = Qb + head + (size_t)(q0 + lo) * DH_ + hi * 8;
#pragma unroll
    for (int ks = 0; ks < 8; ++ks) qf[ks] = *(const bf16x8*)(qp + ks * 16);
  }
  f32x16 oacc[4];
#pragma unroll
  for (int dt = 0; dt < 4; ++dt)
#pragma unroll
    for (int i = 0; i < 16; ++i) oacc[dt][i] = 0.f;
  float mrun = -1e30f, lrun = 0.f;

  const u16* kg0 = Kb + head + (size_t)(t >> 4) * DH_ + (t & 15) * 8;
  const u16* vg0 = Vt + head + (size_t)(t >> 3) * SQ_ + (t & 7) * 8;
  const int swz = (lo & 7) << 3;

#define STAGE(buf, kt)                                                   \
  do {                                                                   \
    const u16* kg_ = kg0 + (size_t)(kt) * 64 * DH_;                      \
    _Pragma("unroll")                                                    \
    for (int r_ = 0; r_ < 4; ++r_)                                       \
      gld16(kg_ + (size_t)r_ * 16 * DH_, &Ks[buf][t * 8 + r_ * 2048]);   \
    const u16* vg_ = vg0 + (kt) * 64;                                    \
    _Pragma("unroll")                                                    \
    for (int r_ = 0; r_ < 4; ++r_)                                       \
      gld16(vg_ + (size_t)r_ * 32 * SQ_, &Vs[buf][t * 8 + r_ * 2048]);   \
  } while (0)

  STAGE(0, 0);
  const int nt = SQ_ / 64;  // 36
  for (int kt = 0; kt < nt; ++kt) {
    const int cur = kt & 1;
    if (kt + 1 < nt) {
      STAGE(cur ^ 1, kt + 1);
      asm volatile("s_waitcnt vmcnt(8)" ::: "memory");
    } else {
      asm volatile("s_waitcnt vmcnt(0)" ::: "memory");
    }
    __builtin_amdgcn_s_barrier();

    f32x16 sv0, sv1;
#pragma unroll
    for (int i = 0; i < 16; ++i) { sv0[i] = 0.f; sv1[i] = 0.f; }
#pragma unroll
    for (int ks = 0; ks < 8; ++ks) {
      bf16x8 kf = *(const bf16x8*)&Ks[cur][lo * DH_ + ((ks * 16 + hi * 8) ^ swz)];
      sv0 = __builtin_amdgcn_mfma_f32_32x32x16_bf16(kf, qf[ks], sv0, 0, 0, 0);
    }
#pragma unroll
    for (int ks = 0; ks < 8; ++ks) {
      bf16x8 kf = *(const bf16x8*)&Ks[cur][(32 + lo) * DH_ + ((ks * 16 + hi * 8) ^ swz)];
      sv1 = __builtin_amdgcn_mfma_f32_32x32x16_bf16(kf, qf[ks], sv1, 0, 0, 0);
    }

    float tm = sv0[0];
#pragma unroll
    for (int i = 1; i < 16; ++i) tm = fmaxf(tm, sv0[i]);
#pragma unroll
    for (int i = 0; i < 16; ++i) tm = fmaxf(tm, sv1[i]);
    tm = fmaxf(tm, __shfl_xor(tm, 32));
    const float sc = tm * SL_;
    if (!__all(sc - mrun <= 8.0f)) {
      const float mn = fmaxf(mrun, sc);
      const float scl = __builtin_amdgcn_exp2f(mrun - mn);
      mrun = mn;
      lrun *= scl;
#pragma unroll
      for (int dt = 0; dt < 4; ++dt)
#pragma unroll
        for (int i = 0; i < 16; ++i) oacc[dt][i] *= scl;
    }
    float p0[16], p1[16];
    float rs = 0.f;
#pragma unroll
    for (int i = 0; i < 16; ++i) {
      p0[i] = __builtin_amdgcn_exp2f(fmaf(sv0[i], SL_, -mrun));
      rs += p0[i];
    }
#pragma unroll
    for (int i = 0; i < 16; ++i) {
      p1[i] = __builtin_amdgcn_exp2f(fmaf(sv1[i], SL_, -mrun));
      rs += p1[i];
    }
    rs += __shfl_xor(rs, 32);
    lrun += rs;

    unsigned xx[16];
#pragma unroll
    for (int g = 0; g < 8; ++g) xx[g] = cvt_pk_bf16(p0[2 * g], p0[2 * g + 1]);
#pragma unroll
    for (int g = 0; g < 8; ++g) xx[8 + g] = cvt_pk_bf16(p1[2 * g], p1[2 * g + 1]);
#pragma unroll
    for (int b = 0; b < 16; b += 4) {
      asm("v_permlane32_swap_b32 %0, %1" : "+v"(xx[b]), "+v"(xx[b + 2]));
      asm("v_permlane32_swap_b32 %0, %1" : "+v"(xx[b + 1]), "+v"(xx[b + 3]));
    }
    bf16x8 pb[4];
#pragma unroll
    for (int st = 0; st < 4; ++st) {
      union { unsigned u[4]; bf16x8 b; } cv;
      cv.u[0] = xx[4 * st]; cv.u[1] = xx[4 * st + 1];
      cv.u[2] = xx[4 * st + 2]; cv.u[3] = xx[4 * st + 3];
      pb[st] = cv.b;
    }

#pragma unroll
    for (int dt = 0; dt < 4; ++dt) {
      const int drow = dt * 32 + lo;
#pragma unroll
      for (int st = 0; st < 4; ++st) {
        bf16x8 vf = *(const bf16x8*)&Vs[cur][drow * 64 + ((st * 16 + hi * 8) ^ swz)];
        oacc[dt] = __builtin_amdgcn_mfma_f32_32x32x16_bf16(vf, pb[st], oacc[dt], 0, 0, 0);
      }
    }
    __builtin_amdgcn_s_barrier();
  }
#undef STAGE

  const float rinv = 1.0f / lrun;
  u16* op = attnb + (size_t)(q0 + lo) * DIM_ + h * DH_ + hi * 4;
#pragma unroll
  for (int dt = 0; dt < 4; ++dt)
#pragma unroll
    for (int g = 0; g < 4; ++g) {
      uint2 u;
      u.x = cvt_pk_bf16(oacc[dt][4 * g + 0] * rinv, oacc[dt][4 * g + 1] * rinv);
      u.y = cvt_pk_bf16(oacc[dt][4 * g + 2] * rinv, oacc[dt][4 * g + 3] * rinv);
      *(uint2*)(op + dt * 32 + g * 8) = u;
    }
}

extern "C" void kernel_launch(void* const* d_in, const int* in_sizes, int n_in,
                              void* d_out, int out_size, void* d_ws, size_t ws_size,
                              hipStream_t stream) {
  (void)in_sizes; (void)n_in; (void)out_size; (void)ws_size;
  const float* hidden    = (const float*)d_in[0];
  const float* encoder   = (const float*)d_in[1];
  const float* vid_cos   = (const float*)d_in[2];
  const float* vid_sin   = (const float*)d_in[3];
  const float* txt_cos   = (const float*)d_in[4];
  const float* txt_sin   = (const float*)d_in[5];
  const float* w_qkv     = (const float*)d_in[6];
  const float* b_qkv     = (const float*)d_in[7];
  const float* w_add_qkv = (const float*)d_in[8];
  const float* b_add_qkv = (const float*)d_in[9];
  const float* norm_q_w  = (const float*)d_in[10];
  const float* norm_k_w  = (const float*)d_in[11];
  const float* norm_aq_w = (const float*)d_in[12];
  const float* norm_ak_w = (const float*)d_in[13];
  const float* w_out     = (const float*)d_in[14];
  const float* b_out     = (const float*)d_in[15];
  const float* w_add_out = (const float*)d_in[16];
  const float* b_add_out = (const float*)d_in[17];
  float* out = (float*)d_out;

  char* ws = (char*)d_ws;
  u16* wqkv_t    = (u16*)(ws + 0);            // 9216x3072 bf16
  u16* waddqkv_t = (u16*)(ws + 56623104);
  u16* img_qkv   = (u16*)(ws + 113246208);    // 2048x9216
  u16* txt_qkv   = (u16*)(ws + 150994944);    // 256x9216
  u16* Qb        = (u16*)(ws + 155713536);    // 24x2304x128
  u16* Kb        = (u16*)(ws + 169869312);
  u16* Vt        = (u16*)(ws + 184025088);    // end 198,180,864
  u16* wout_t    = wqkv_t;
  u16* waddout_t = waddqkv_t;
  u16* attnb     = img_qkv;
  u16* hidden_bf = Qb;
  u16* encoder_bf = Kb;

  // 0) f2b of both activations + both qkv weight transposes (one launch)
  k_pre<<<(SIMG_ * DIM_ + STXT_ * DIM_) / 1024 +
              2 * (NQKV_ / 64) * (DIM_ / 64),
          256, 0, stream>>>(hidden, hidden_bf, SIMG_ * DIM_,
                            encoder, encoder_bf, STXT_ * DIM_,
                            w_qkv, wqkv_t, w_add_qkv, waddqkv_t);
  // 1) img + txt QKV projections fused
  k_gemm_bt2<false><<<(SIMG_ / 128 + STXT_ / 128) * (NQKV_ / 128), 256, 0, stream>>>(
      hidden_bf, wqkv_t, b_qkv, img_qkv, SIMG_,
      encoder_bf, waddqkv_t, b_add_qkv, txt_qkv, STXT_,
      NQKV_, DIM_, (SIMG_ / 128) * (NQKV_ / 128));
  // 2) merged V-transpose + rmsnorm/rope
  k_prep<<<(SQ_ / 64) * H_ + (SQ_ * H_) / 4, 256, 0, stream>>>(
      img_qkv, txt_qkv, vid_cos, vid_sin, txt_cos, txt_sin,
      norm_q_w, norm_k_w, norm_aq_w, norm_ak_w, Qb, Kb, Vt);
  // 3) attention + out-proj weight transposes (one launch)
  k_attn_f<<<(SQ_ / 128) * H_ + 2 * (DIM_ / 64) * (DIM_ / 64), 256, 0, stream>>>(
      Qb, Kb, Vt, attnb, w_out, wout_t, w_add_out, waddout_t);
  // 4) img + txt output projections fused (fp32 out)
  k_gemm_bt2<true><<<(SIMG_ / 128 + STXT_ / 128) * (DIM_ / 128), 256, 0, stream>>>(
      attnb + (size_t)STXT_ * DIM_, wout_t, b_out, out, SIMG_,
      attnb, waddout_t, b_add_out, out + (size_t)SIMG_ * DIM_, STXT_,
      DIM_, DIM_, (SIMG_ / 128) * (DIM_ / 128));
}

// Round 21
// 412.395 us; speedup vs baseline: 1.0669x; 1.0669x over previous
//
#include <hip/hip_runtime.h>

typedef unsigned short u16;
typedef __attribute__((ext_vector_type(8))) short bf16x8;
typedef __attribute__((ext_vector_type(4))) float f32x4;
typedef __attribute__((ext_vector_type(16))) float f32x16;

#define H_    24
#define DH_   128
#define DIM_  3072
#define NQKV_ 9216
#define SIMG_ 2048
#define STXT_ 256
#define SQ_   2304
#define SL_   0.1275258646912204f

__device__ __forceinline__ float bf2f(u16 h) {
  union { unsigned u; float f; } x; x.u = ((unsigned)h) << 16; return x.f;
}
__device__ __forceinline__ u16 f2bf(float f) {
  union { float f; unsigned u; } x; x.f = f;
  unsigned r = x.u + 0x7FFFu + ((x.u >> 16) & 1u);
  return (u16)(r >> 16);
}
__device__ __forceinline__ unsigned cvt_pk_bf16(float lo, float hi) {
  unsigned r;
  asm("v_cvt_pk_bf16_f32 %0, %1, %2" : "=v"(r) : "v"(lo), "v"(hi));
  return r;
}

__device__ __forceinline__ void gld16(const u16* g, u16* l) {
  __builtin_amdgcn_global_load_lds(
      (const __attribute__((address_space(1))) unsigned*)g,
      (__attribute__((address_space(3))) unsigned*)l, 16, 0, 0);
}

// shared transpose tile body (fp32 [R][C] -> bf16 [C][R], 64x64)
__device__ __forceinline__ void transpose_tile(const float* __restrict__ in,
                                               u16* __restrict__ out,
                                               int R, int C, int bc, int br,
                                               u16 (*tile)[72], int t) {
  const int tx = t & 15, ty = t >> 4;
#pragma unroll
  for (int i = 0; i < 4; ++i) {
    const int r = ty + i * 16;
    float4 v = *(const float4*)(in + (size_t)(br + r) * C + bc + tx * 4);
    ushort4 o;
    o.x = f2bf(v.x); o.y = f2bf(v.y); o.z = f2bf(v.z); o.w = f2bf(v.w);
    *(ushort4*)&tile[r][tx * 4] = o;
  }
  __syncthreads();
#pragma unroll
  for (int i = 0; i < 4; ++i) {
    const int c = ty + i * 16;
    ushort4 v;
    v.x = tile[tx * 4 + 0][c];
    v.y = tile[tx * 4 + 1][c];
    v.z = tile[tx * 4 + 2][c];
    v.w = tile[tx * 4 + 3][c];
    *(ushort4*)(out + (size_t)(bc + c) * R + br + tx * 4) = v;
  }
}

// ===== k_pre: f2b of both activations + both QKV weight transposes =========
__global__ __launch_bounds__(256) void k_pre(
    const float* __restrict__ hidden, u16* __restrict__ hidden_bf, int n0,
    const float* __restrict__ encoder, u16* __restrict__ encoder_bf, int n1,
    const float* __restrict__ w0, u16* __restrict__ wt0,
    const float* __restrict__ w1, u16* __restrict__ wt1) {
  __shared__ __align__(16) u16 tile[64][72];
  const int t = threadIdx.x;
  const int nf2b = (n0 + n1) / 1024;
  if ((int)blockIdx.x < nf2b) {
    int i = (blockIdx.x * 256 + t) * 4;
    const float* in = hidden;
    u16* out = hidden_bf;
    int n = n0;
    if (i >= n0) { i -= n0; in = encoder; out = encoder_bf; n = n1; }
    if (i < n) {
      float4 v = *(const float4*)(in + i);
      ushort4 o;
      o.x = f2bf(v.x); o.y = f2bf(v.y); o.z = f2bf(v.z); o.w = f2bf(v.w);
      *(ushort4*)(out + i) = o;
    }
    return;
  }
  const int blk = blockIdx.x - nf2b;
  const int nxy = (NQKV_ / 64) * (DIM_ / 64);  // 144*48 per weight
  const int z = blk / nxy, rem = blk % nxy;
  const int bx = rem % (NQKV_ / 64), by = rem / (NQKV_ / 64);
  transpose_tile(z ? w1 : w0, z ? wt1 : wt0, DIM_, NQKV_,
                 bx * 64, by * 64, tile, t);
}

// --------- GEMM 128x128, BK=32, TRIPLE-buffered LDS, ONE barrier per K-tile.
// WAR race removed structurally: iter i stages tile i+1 into buf[(i+1)%3],
// reads buf[i%3]; concurrent windows only touch (i+1)%3/(i+2)%3 != i%3.
// vmcnt(4) before the barrier guarantees tile i landed block-wide.
// TWO problems fused per launch (tail-filling demux). ------------------------
template <bool F32OUT>
__global__ __launch_bounds__(256) void k_gemm_bt2(const u16* __restrict__ A0,
                                                  const u16* __restrict__ Bt0,
                                                  const float* __restrict__ bias0,
                                                  void* __restrict__ C0,
                                                  int M0,
                                                  const u16* __restrict__ A1,
                                                  const u16* __restrict__ Bt1,
                                                  const float* __restrict__ bias1,
                                                  void* __restrict__ C1,
                                                  int M1,
                                                  int N, int K, int nblk0) {
  __shared__ __align__(16) u16 As[3][128 * 32];  // 24 KB
  __shared__ __align__(16) u16 Bs[3][128 * 32];  // 24 KB
  const int t = threadIdx.x, w = t >> 6, l = t & 63;
  const int lr = l & 15, lg = l >> 4;
  const int wr = w >> 1, wc = w & 1;

  const u16 *A, *Bt;
  const float* bias;
  void* Cv;
  int M, wg, nwg;
  if ((int)blockIdx.x < nblk0) {
    A = A0; Bt = Bt0; bias = bias0; Cv = C0; M = M0;
    wg = blockIdx.x; nwg = nblk0;
  } else {
    A = A1; Bt = Bt1; bias = bias1; Cv = C1; M = M1;
    wg = blockIdx.x - nblk0; nwg = gridDim.x - nblk0;
  }
  const int nbm = M >> 7;
  if ((nwg & 7) == 0) {
    const int c = nwg >> 3;
    wg = (wg & 7) * c + (wg >> 3);
  }
  const int bm = (wg % nbm) * 128, bn = (wg / nbm) * 128;

  f32x4 acc[4][4];
#pragma unroll
  for (int i = 0; i < 4; ++i)
#pragma unroll
    for (int j = 0; j < 4; ++j) acc[i][j] = (f32x4){0.f, 0.f, 0.f, 0.f};

  const u16* Ag = A + (size_t)(bm + (t >> 2)) * K + (t & 3) * 8;
  const u16* Bg = Bt + (size_t)(bn + (t >> 2)) * K + (t & 3) * 8;

#define GSTAGE(buf)                                        \
  do {                                                     \
    gld16(Ag, &As[buf][t * 8]);                            \
    gld16(Ag + (size_t)64 * K, &As[buf][t * 8 + 2048]);    \
    gld16(Bg, &Bs[buf][t * 8]);                            \
    gld16(Bg + (size_t)64 * K, &Bs[buf][t * 8 + 2048]);    \
    Ag += 32; Bg += 32;                                    \
  } while (0)

  GSTAGE(0);  // tile 0 -> buf 0
  const int nt = K >> 5;
  int cur = 0, nxt = 1;
  for (int tile = 0; tile < nt; ++tile) {
    if (tile + 1 < nt) {
      GSTAGE(nxt);  // tile+1 -> buf (tile+1)%3
      asm volatile("s_waitcnt vmcnt(4)" ::: "memory");
    } else {
      asm volatile("s_waitcnt vmcnt(0)" ::: "memory");
    }
    __builtin_amdgcn_s_barrier();
    bf16x8 af[4], bfr[4];
#pragma unroll
    for (int i = 0; i < 4; ++i)
      af[i] = *(const bf16x8*)&As[cur][(wr * 64 + i * 16 + lr) * 32 + lg * 8];
#pragma unroll
    for (int j = 0; j < 4; ++j)
      bfr[j] = *(const bf16x8*)&Bs[cur][(wc * 64 + j * 16 + lr) * 32 + lg * 8];
#pragma unroll
    for (int i = 0; i < 4; ++i)
#pragma unroll
      for (int j = 0; j < 4; ++j)
        acc[i][j] = __builtin_amdgcn_mfma_f32_16x16x32_bf16(af[i], bfr[j], acc[i][j], 0, 0, 0);
    // no post-MFMA barrier: tri-buffer makes the WAR impossible
    cur = nxt;
    nxt = nxt + 1;
    if (nxt == 3) nxt = 0;
  }
#undef GSTAGE

#pragma unroll
  for (int j = 0; j < 4; ++j) {
    const int col = bn + wc * 64 + j * 16 + lr;
    const float bv = bias[col];
#pragma unroll
    for (int i = 0; i < 4; ++i) {
      const int row = bm + wr * 64 + i * 16 + lg * 4;
#pragma unroll
      for (int r = 0; r < 4; ++r) {
        const float v = acc[i][j][r] + bv;
        if constexpr (F32OUT)
          ((float*)Cv)[(size_t)(row + r) * N + col] = v;
        else
          ((u16*)Cv)[(size_t)(row + r) * N + col] = f2bf(v);
      }
    }
  }
}

// ===== k_prep: merged (k_vt | k_norm_rope) via block-range demux ============
__global__ __launch_bounds__(256) void k_prep(
    const u16* __restrict__ img_qkv, const u16* __restrict__ txt_qkv,
    const float* __restrict__ vid_cos, const float* __restrict__ vid_sin,
    const float* __restrict__ txt_cos, const float* __restrict__ txt_sin,
    const float* __restrict__ nq, const float* __restrict__ nk,
    const float* __restrict__ naq, const float* __restrict__ nak,
    u16* __restrict__ Qb, u16* __restrict__ Kb, u16* __restrict__ Vt) {
  __shared__ __align__(16) u16 tile[64][136];
  const int t = threadIdx.x;
  if (blockIdx.x < (SQ_ / 64) * H_) {
    const int h = blockIdx.x / (SQ_ / 64), sb = blockIdx.x % (SQ_ / 64);
    {
      const int row = t >> 2, cc = (t & 3) * 32;
      const int s = sb * 64 + row;
      const u16* src = (s < STXT_) ? (txt_qkv + (size_t)s * NQKV_)
                                   : (img_qkv + (size_t)(s - STXT_) * NQKV_);
      src += 2 * DIM_ + h * DH_ + cc;
#pragma unroll
      for (int u = 0; u < 4; ++u) {
        uint4 a = *(const uint4*)(src + u * 8);
        *(uint4*)&tile[row][cc + u * 8] = a;
      }
    }
    __syncthreads();
    {
      const int w = t >> 6, lane = t & 63;
#pragma unroll 4
      for (int dd = 0; dd < 32; ++dd) {
        const int d = w * 32 + dd;
        const int m = (d & 7) << 3;
        const u16 v = tile[lane][d];
        Vt[((size_t)h * DH_ + d) * SQ_ + sb * 64 + (lane ^ m)] = v;
      }
    }
    return;
  }
  const int wid = (blockIdx.x - (SQ_ / 64) * H_) * 4 + (t >> 6);
  const int lane = t & 63;
  const int h = wid % H_, s = wid / H_;

  const u16* src;
  const float *cp, *sp, *qw, *kw;
  if (s < STXT_) {
    src = txt_qkv + (size_t)s * NQKV_;
    cp = txt_cos + s * 64; sp = txt_sin + s * 64;
    qw = naq; kw = nak;
  } else {
    const int si = s - STXT_;
    src = img_qkv + (size_t)si * NQKV_;
    cp = vid_cos + si * 64; sp = vid_sin + si * 64;
    qw = nq; kw = nk;
  }
  const float c = cp[lane], sn = sp[lane];
  const size_t drow = ((size_t)h * SQ_ + s) * DH_;

  {
    ushort2 p = *(const ushort2*)(src + h * DH_ + 2 * lane);
    float x1 = bf2f(p.x), x2 = bf2f(p.y);
    float ss = x1 * x1 + x2 * x2;
#pragma unroll
    for (int m = 1; m < 64; m <<= 1) ss += __shfl_xor(ss, m);
    const float rr = rsqrtf(ss * (1.0f / 128.0f) + 1e-6f);
    const float xn1 = x1 * rr * qw[2 * lane];
    const float xn2 = x2 * rr * qw[2 * lane + 1];
    ushort2 o; o.x = f2bf(xn1 * c - xn2 * sn); o.y = f2bf(xn2 * c + xn1 * sn);
    *(ushort2*)(Qb + drow + 2 * lane) = o;
  }
  {
    ushort2 p = *(const ushort2*)(src + DIM_ + h * DH_ + 2 * lane);
    float x1 = bf2f(p.x), x2 = bf2f(p.y);
    float ss = x1 * x1 + x2 * x2;
#pragma unroll
    for (int m = 1; m < 64; m <<= 1) ss += __shfl_xor(ss, m);
    const float rr = rsqrtf(ss * (1.0f / 128.0f) + 1e-6f);
    const float xn1 = x1 * rr * kw[2 * lane];
    const float xn2 = x2 * rr * kw[2 * lane + 1];
    ushort2 o; o.x = f2bf(xn1 * c - xn2 * sn); o.y = f2bf(xn2 * c + xn1 * sn);
    const int col = (2 * lane) ^ ((s & 7) << 3);
    *(ushort2*)(Kb + drow + col) = o;
  }
}

// === k_attn_f: flash attention + out-weight transposes in ONE launch ========
__global__ __launch_bounds__(256, 2) void k_attn_f(
    const u16* __restrict__ Qb, const u16* __restrict__ Kb,
    const u16* __restrict__ Vt, u16* __restrict__ attnb,
    const float* __restrict__ w0, u16* __restrict__ wt0,
    const float* __restrict__ w1, u16* __restrict__ wt1) {
  __shared__ __align__(16) u16 Ks[2][64 * 128];
  __shared__ __align__(16) u16 Vs[2][128 * 64];
  const int t = threadIdx.x;
  if (blockIdx.x >= (SQ_ / 128) * H_) {
    const int blk = blockIdx.x - (SQ_ / 128) * H_;
    const int nxy = (DIM_ / 64) * (DIM_ / 64);  // 2304
    const int z = blk / nxy, rem = blk % nxy;
    const int bx = rem % (DIM_ / 64), by = rem / (DIM_ / 64);
    u16 (*tile)[72] = (u16(*)[72]) & Ks[0][0];
    transpose_tile(z ? w1 : w0, z ? wt1 : wt0, DIM_, DIM_,
                   bx * 64, by * 64, tile, t);
    return;
  }
  const int w = t >> 6, l = t & 63;
  const int lo = l & 31, hi = l >> 5;

  const int bid = blockIdx.x;
  const int xcd = bid & 7, jj = bid >> 3;
  const int h = xcd * 3 + jj / 18;
  const int qb = jj % 18;

  const int q0 = qb * 128 + w * 32;
  const size_t head = (size_t)h * SQ_ * DH_;

  bf16x8 qf[8];
  {
    const u16* qp = Qb + head + (size_t)(q0 + lo) * DH_ + hi * 8;
#pragma unroll
    for (int ks = 0; ks < 8; ++ks) qf[ks] = *(const bf16x8*)(qp + ks * 16);
  }
  f32x16 oacc[4];
#pragma unroll
  for (int dt = 0; dt < 4; ++dt)
#pragma unroll
    for (int i = 0; i < 16; ++i) oacc[dt][i] = 0.f;
  float mrun = -1e30f, lrun = 0.f;

  const u16* kg0 = Kb + head + (size_t)(t >> 4) * DH_ + (t & 15) * 8;
  const u16* vg0 = Vt + head + (size_t)(t >> 3) * SQ_ + (t & 7) * 8;
  const int swz = (lo & 7) << 3;

#define STAGE(buf, kt)                                                   \
  do {                                                                   \
    const u16* kg_ = kg0 + (size_t)(kt) * 64 * DH_;                      \
    _Pragma("unroll")                                                    \
    for (int r_ = 0; r_ < 4; ++r_)                                       \
      gld16(kg_ + (size_t)r_ * 16 * DH_, &Ks[buf][t * 8 + r_ * 2048]);   \
    const u16* vg_ = vg0 + (kt) * 64;                                    \
    _Pragma("unroll")                                                    \
    for (int r_ = 0; r_ < 4; ++r_)                                       \
      gld16(vg_ + (size_t)r_ * 32 * SQ_, &Vs[buf][t * 8 + r_ * 2048]);   \
  } while (0)

  STAGE(0, 0);
  const int nt = SQ_ / 64;  // 36
  for (int kt = 0; kt < nt; ++kt) {
    const int cur = kt & 1;
    if (kt + 1 < nt) {
      STAGE(cur ^ 1, kt + 1);
      asm volatile("s_waitcnt vmcnt(8)" ::: "memory");
    } else {
      asm volatile("s_waitcnt vmcnt(0)" ::: "memory");
    }
    __builtin_amdgcn_s_barrier();

    f32x16 sv0, sv1;
#pragma unroll
    for (int i = 0; i < 16; ++i) { sv0[i] = 0.f; sv1[i] = 0.f; }
#pragma unroll
    for (int ks = 0; ks < 8; ++ks) {
      bf16x8 kf = *(const bf16x8*)&Ks[cur][lo * DH_ + ((ks * 16 + hi * 8) ^ swz)];
      sv0 = __builtin_amdgcn_mfma_f32_32x32x16_bf16(kf, qf[ks], sv0, 0, 0, 0);
    }
#pragma unroll
    for (int ks = 0; ks < 8; ++ks) {
      bf16x8 kf = *(const bf16x8*)&Ks[cur][(32 + lo) * DH_ + ((ks * 16 + hi * 8) ^ swz)];
      sv1 = __builtin_amdgcn_mfma_f32_32x32x16_bf16(kf, qf[ks], sv1, 0, 0, 0);
    }

    float tm = sv0[0];
#pragma unroll
    for (int i = 1; i < 16; ++i) tm = fmaxf(tm, sv0[i]);
#pragma unroll
    for (int i = 0; i < 16; ++i) tm = fmaxf(tm, sv1[i]);
    tm = fmaxf(tm, __shfl_xor(tm, 32));
    const float sc = tm * SL_;
    if (!__all(sc - mrun <= 8.0f)) {
      const float mn = fmaxf(mrun, sc);
      const float scl = __builtin_amdgcn_exp2f(mrun - mn);
      mrun = mn;
      lrun *= scl;
#pragma unroll
      for (int dt = 0; dt < 4; ++dt)
#pragma unroll
        for (int i = 0; i < 16; ++i) oacc[dt][i] *= scl;
    }
    float p0[16], p1[16];
    float rs = 0.f;
#pragma unroll
    for (int i = 0; i < 16; ++i) {
      p0[i] = __builtin_amdgcn_exp2f(fmaf(sv0[i], SL_, -mrun));
      rs += p0[i];
    }
#pragma unroll
    for (int i = 0; i < 16; ++i) {
      p1[i] = __builtin_amdgcn_exp2f(fmaf(sv1[i], SL_, -mrun));
      rs += p1[i];
    }
    rs += __shfl_xor(rs, 32);
    lrun += rs;

    unsigned xx[16];
#pragma unroll
    for (int g = 0; g < 8; ++g) xx[g] = cvt_pk_bf16(p0[2 * g], p0[2 * g + 1]);
#pragma unroll
    for (int g = 0; g < 8; ++g) xx[8 + g] = cvt_pk_bf16(p1[2 * g], p1[2 * g + 1]);
#pragma unroll
    for (int b = 0; b < 16; b += 4) {
      asm("v_permlane32_swap_b32 %0, %1" : "+v"(xx[b]), "+v"(xx[b + 2]));
      asm("v_permlane32_swap_b32 %0, %1" : "+v"(xx[b + 1]), "+v"(xx[b + 3]));
    }
    bf16x8 pb[4];
#pragma unroll
    for (int st = 0; st < 4; ++st) {
      union { unsigned u[4]; bf16x8 b; } cv;
      cv.u[0] = xx[4 * st]; cv.u[1] = xx[4 * st + 1];
      cv.u[2] = xx[4 * st + 2]; cv.u[3] = xx[4 * st + 3];
      pb[st] = cv.b;
    }

#pragma unroll
    for (int dt = 0; dt < 4; ++dt) {
      const int drow = dt * 32 + lo;
#pragma unroll
      for (int st = 0; st < 4; ++st) {
        bf16x8 vf = *(const bf16x8*)&Vs[cur][drow * 64 + ((st * 16 + hi * 8) ^ swz)];
        oacc[dt] = __builtin_amdgcn_mfma_f32_32x32x16_bf16(vf, pb[st], oacc[dt], 0, 0, 0);
      }
    }
    __builtin_amdgcn_s_barrier();
  }
#undef STAGE

  const float rinv = 1.0f / lrun;
  u16* op = attnb + (size_t)(q0 + lo) * DIM_ + h * DH_ + hi * 4;
#pragma unroll
  for (int dt = 0; dt < 4; ++dt)
#pragma unroll
    for (int g = 0; g < 4; ++g) {
      uint2 u;
      u.x = cvt_pk_bf16(oacc[dt][4 * g + 0] * rinv, oacc[dt][4 * g + 1] * rinv);
      u.y = cvt_pk_bf16(oacc[dt][4 * g + 2] * rinv, oacc[dt][4 * g + 3] * rinv);
      *(uint2*)(op + dt * 32 + g * 8) = u;
    }
}

extern "C" void kernel_launch(void* const* d_in, const int* in_sizes, int n_in,
                              void* d_out, int out_size, void* d_ws, size_t ws_size,
                              hipStream_t stream) {
  (void)in_sizes; (void)n_in; (void)out_size; (void)ws_size;
  const float* hidden    = (const float*)d_in[0];
  const float* encoder   = (const float*)d_in[1];
  const float* vid_cos   = (const float*)d_in[2];
  const float* vid_sin   = (const float*)d_in[3];
  const float* txt_cos   = (const float*)d_in[4];
  const float* txt_sin   = (const float*)d_in[5];
  const float* w_qkv     = (const float*)d_in[6];
  const float* b_qkv     = (const float*)d_in[7];
  const float* w_add_qkv = (const float*)d_in[8];
  const float* b_add_qkv = (const float*)d_in[9];
  const float* norm_q_w  = (const float*)d_in[10];
  const float* norm_k_w  = (const float*)d_in[11];
  const float* norm_aq_w = (const float*)d_in[12];
  const float* norm_ak_w = (const float*)d_in[13];
  const float* w_out     = (const float*)d_in[14];
  const float* b_out     = (const float*)d_in[15];
  const float* w_add_out = (const float*)d_in[16];
  const float* b_add_out = (const float*)d_in[17];
  float* out = (float*)d_out;

  char* ws = (char*)d_ws;
  u16* wqkv_t    = (u16*)(ws + 0);            // 9216x3072 bf16
  u16* waddqkv_t = (u16*)(ws + 56623104);
  u16* img_qkv   = (u16*)(ws + 113246208);    // 2048x9216
  u16* txt_qkv   = (u16*)(ws + 150994944);    // 256x9216
  u16* Qb        = (u16*)(ws + 155713536);    // 24x2304x128
  u16* Kb        = (u16*)(ws + 169869312);
  u16* Vt        = (u16*)(ws + 184025088);    // end 198,180,864
  u16* wout_t    = wqkv_t;
  u16* waddout_t = waddqkv_t;
  u16* attnb     = img_qkv;
  u16* hidden_bf = Qb;
  u16* encoder_bf = Kb;

  // 0) f2b of both activations + both qkv weight transposes (one launch)
  k_pre<<<(SIMG_ * DIM_ + STXT_ * DIM_) / 1024 +
              2 * (NQKV_ / 64) * (DIM_ / 64),
          256, 0, stream>>>(hidden, hidden_bf, SIMG_ * DIM_,
                            encoder, encoder_bf, STXT_ * DIM_,
                            w_qkv, wqkv_t, w_add_qkv, waddqkv_t);
  // 1) img + txt QKV projections fused
  k_gemm_bt2<false><<<(SIMG_ / 128 + STXT_ / 128) * (NQKV_ / 128), 256, 0, stream>>>(
      hidden_bf, wqkv_t, b_qkv, img_qkv, SIMG_,
      encoder_bf, waddqkv_t, b_add_qkv, txt_qkv, STXT_,
      NQKV_, DIM_, (SIMG_ / 128) * (NQKV_ / 128));
  // 2) merged V-transpose + rmsnorm/rope
  k_prep<<<(SQ_ / 64) * H_ + (SQ_ * H_) / 4, 256, 0, stream>>>(
      img_qkv, txt_qkv, vid_cos, vid_sin, txt_cos, txt_sin,
      norm_q_w, norm_k_w, norm_aq_w, norm_ak_w, Qb, Kb, Vt);
  // 3) attention + out-proj weight transposes (one launch)
  k_attn_f<<<(SQ_ / 128) * H_ + 2 * (DIM_ / 64) * (DIM_ / 64), 256, 0, stream>>>(
      Qb, Kb, Vt, attnb, w_out, wout_t, w_add_out, waddout_t);
  // 4) img + txt output projections fused (fp32 out)
  k_gemm_bt2<true><<<(SIMG_ / 128 + STXT_ / 128) * (DIM_ / 128), 256, 0, stream>>>(
      attnb + (size_t)STXT_ * DIM_, wout_t, b_out, out, SIMG_,
      attnb, waddout_t, b_add_out, out + (size_t)SIMG_ * DIM_, STXT_,
      DIM_, DIM_, (SIMG_ / 128) * (DIM_ / 128));
}